// Round 2
// baseline (594.996 us; speedup 1.0000x reference)
//
#include <hip/hip_runtime.h>
#include <math.h>

// RoutingCapsules — B=16, I=2048, K=64, J=64, D=32, 3 routing iters.
//   s[b,j,d]  = sum_k W[j,d,k] y[b,j,k],    y[b,j,k]  = sum_i c[b,j,i] x[b,i,k]
//   uv[b,j,i] = sum_k x[b,i,k] wv[b,j,k],   wv[b,j,k] = sum_d W[j,d,k] v[b,j,d]
// Iter-1 c uniform -> y1 = (1/64) sum_i x.  Logits linear in wv -> wv2 = wv1+dwv.
//
// R3: SINGLE fused kernel. grid (b,t)=512 blocks, all co-resident (54.5KB LDS
// -> 2 blocks/CU). Per-b chain: ybar partial -> [last 8 blocks: caps0 -> wv1]
// -> flag1 -> route1 -> [last 8: caps1 -> wv] -> flag2 -> route2 -> [last 8:
// caps2 -> out]. x tile staged in LDS ONCE, reused by ybar + both routes.
// Different b's pipeline across the chip; 6 launches -> 1.

#define BB 16
#define II 2048
#define KK 64
#define JJ 64
#define DD 32
#define ITILE 64
#define NT 32              // i-tiles per b
#define NCAPS 8            // tail blocks per b doing caps
#define JPC (JJ / NCAPS)   // 8 j per caps block
#define JPW (JPC / 4)      // 2 j per wave

#define SCRATCH_FLOATS ((KK + JJ) * 68 + 8 * 72)   // 9280 floats = 37120 B

// ---------------------------------------------------------------------------
// caps tail: chunk of 8 j, 2 j per wave. Wave-private LDS (no syncthreads).
//   MODE 0: y = (1/64)*sum_t ybar-partials (j-indep); wv  = W^T v
//   MODE 1: y = sum_t ypart[t][j];                    wv += W^T v
//   MODE 2: y = sum_t ypart[t][j];                    out = squash(s)
// ---------------------------------------------------------------------------
template <int MODE>
__device__ __forceinline__ void caps_tail(int b, int chunk,
                                          const float* __restrict__ W,
                                          const float* __restrict__ ypb,
                                          float* __restrict__ wvb,
                                          float* __restrict__ out,
                                          float* scratch) {
    const int tid = threadIdx.x;
    const int w = tid >> 6, lane = tid & 63;
    float* W_sm = scratch + w * (DD * 68);                 // [32][68]
    float* y_sm = scratch + 4 * (DD * 68) + w * KK;        // [64]
    float* v_sm = scratch + 4 * (DD * 68) + 4 * KK + w * DD;

    if (MODE == 0) {   // y j-independent: compute once per wave
        const int kq = lane & 15, th = lane >> 4;
        float ax = 0.f, ay = 0.f, az = 0.f, aw = 0.f;
        #pragma unroll
        for (int n = 0; n < 8; ++n) {
            const float4 v = *(const float4*)(ypb + (th + n * 4) * KK + kq * 4);
            ax += v.x; ay += v.y; az += v.z; aw += v.w;
        }
        ax += __shfl_xor(ax, 16, 64); ay += __shfl_xor(ay, 16, 64);
        az += __shfl_xor(az, 16, 64); aw += __shfl_xor(aw, 16, 64);
        ax += __shfl_xor(ax, 32, 64); ay += __shfl_xor(ay, 32, 64);
        az += __shfl_xor(az, 32, 64); aw += __shfl_xor(aw, 32, 64);
        if (lane < 16)
            *(float4*)&y_sm[kq * 4] = make_float4(ax * (1.f / 64.f), ay * (1.f / 64.f),
                                                  az * (1.f / 64.f), aw * (1.f / 64.f));
    }

    #pragma unroll
    for (int jj = 0; jj < JPW; ++jj) {
        const int j = chunk * JPC + w * JPW + jj;
        const float* Wp = W + (size_t)j * DD * KK;
        #pragma unroll
        for (int rr = 0; rr < 8; ++rr) {
            const int idx = rr * 64 + lane;
            const int d = idx >> 4, kq = idx & 15;
            *(float4*)&W_sm[d * 68 + kq * 4] = *(const float4*)(Wp + d * KK + kq * 4);
        }
        if (MODE != 0) {   // y[j] = sum of 32 ypart tiles
            const int kq = lane & 15, th = lane >> 4;
            float ax = 0.f, ay = 0.f, az = 0.f, aw = 0.f;
            #pragma unroll
            for (int n = 0; n < 8; ++n) {
                const float4 v = *(const float4*)(ypb +
                    ((size_t)(th + n * 4) * JJ + j) * KK + kq * 4);
                ax += v.x; ay += v.y; az += v.z; aw += v.w;
            }
            ax += __shfl_xor(ax, 16, 64); ay += __shfl_xor(ay, 16, 64);
            az += __shfl_xor(az, 16, 64); aw += __shfl_xor(aw, 16, 64);
            ax += __shfl_xor(ax, 32, 64); ay += __shfl_xor(ay, 32, 64);
            az += __shfl_xor(az, 32, 64); aw += __shfl_xor(aw, 32, 64);
            if (lane < 16) *(float4*)&y_sm[kq * 4] = make_float4(ax, ay, az, aw);
        }

        // s[d] = sum_k W[d][k] y[k] — all 64 lanes: d=lane&31, k-half split
        const int d = lane & 31;
        const int kh = (lane >> 5) * 32;
        float sv = 0.f;
        #pragma unroll
        for (int kq = 0; kq < 8; ++kq) {
            const float4 wr = *(const float4*)&W_sm[d * 68 + kh + kq * 4];
            const float4 yr = *(const float4*)&y_sm[kh + kq * 4];
            sv += wr.x * yr.x + wr.y * yr.y + wr.z * yr.z + wr.w * yr.w;
        }
        sv += __shfl_xor(sv, 32, 64);
        float ps = sv * sv;
        #pragma unroll
        for (int m = 1; m < 32; m <<= 1) ps += __shfl_xor(ps, m, 64);
        const float f = ps / ((1.f + ps) * (sqrtf(ps) + 1e-8f));

        if (MODE == 2) {
            if (lane < DD) out[((size_t)b * JJ + j) * DD + lane] = sv * f;
        } else {
            if (lane < DD) v_sm[lane] = sv * f;
            float a = 0.f;
            #pragma unroll
            for (int dd = 0; dd < DD; ++dd) a += W_sm[dd * 68 + lane] * v_sm[dd];
            const size_t idx = (size_t)j * KK + lane;
            if (MODE == 1) a += wvb[idx];
            wvb[idx] = a;
        }
    }
}

// ---------------------------------------------------------------------------
// route pass: uv = x·wv^T; c = softmax_j; ypt[j][k] = sum_i c[j][i] x[k][i]
// ---------------------------------------------------------------------------
__device__ __forceinline__ void route_pass(const float* __restrict__ wvb,
                                           float* __restrict__ ypt,
                                           float (*x_smT)[68], float* scratch) {
    const int tid = threadIdx.x;
    float (*wv_smT)[68] = (float (*)[68])scratch;
    float (*uv_smT)[68] = (float (*)[68])(scratch + KK * 68);
    float (*red)[72]    = (float (*)[72])(scratch + (KK + JJ) * 68);

    const float4* wv4 = (const float4*)wvb;
    #pragma unroll
    for (int n = 0; n < 4; ++n) {
        const int idx = tid + n * 256;
        const int jj = idx >> 4, kq = idx & 15;
        const float4 v = wv4[idx];
        wv_smT[kq * 4 + 0][jj] = v.x;
        wv_smT[kq * 4 + 1][jj] = v.y;
        wv_smT[kq * 4 + 2][jj] = v.z;
        wv_smT[kq * 4 + 3][jj] = v.w;
    }
    __syncthreads();

    {   // uv[j][i], 4i x 4j per thread, b128 reads
        const int ib = (tid & 15) * 4, jb = (tid >> 4) * 4;
        float acc[4][4] = {};
        for (int k = 0; k < KK; ++k) {
            const float4 xv = *(const float4*)&x_smT[k][ib];
            const float4 wvv = *(const float4*)&wv_smT[k][jb];
            acc[0][0] += xv.x * wvv.x; acc[0][1] += xv.x * wvv.y;
            acc[0][2] += xv.x * wvv.z; acc[0][3] += xv.x * wvv.w;
            acc[1][0] += xv.y * wvv.x; acc[1][1] += xv.y * wvv.y;
            acc[1][2] += xv.y * wvv.z; acc[1][3] += xv.y * wvv.w;
            acc[2][0] += xv.z * wvv.x; acc[2][1] += xv.z * wvv.y;
            acc[2][2] += xv.z * wvv.z; acc[2][3] += xv.z * wvv.w;
            acc[3][0] += xv.w * wvv.x; acc[3][1] += xv.w * wvv.y;
            acc[3][2] += xv.w * wvv.z; acc[3][3] += xv.w * wvv.w;
        }
        #pragma unroll
        for (int r = 0; r < 4; ++r)
            *(float4*)&uv_smT[jb + r][ib] =
                make_float4(acc[0][r], acc[1][r], acc[2][r], acc[3][r]);
    }
    __syncthreads();

    {   // softmax over j (down columns); 16 values per wave in registers
        const int i = tid & 63;
        const int w = tid >> 6;
        const int j0 = w * 16;
        float e[16];
        float m = -1e30f;
        #pragma unroll
        for (int jj = 0; jj < 16; ++jj) {
            e[jj] = uv_smT[j0 + jj][i];
            m = fmaxf(m, e[jj]);
        }
        red[w][i] = m;
        __syncthreads();
        m = fmaxf(fmaxf(red[0][i], red[1][i]), fmaxf(red[2][i], red[3][i]));
        float s = 0.f;
        #pragma unroll
        for (int jj = 0; jj < 16; ++jj) {
            e[jj] = __expf(e[jj] - m);
            s += e[jj];
        }
        red[4 + w][i] = s;
        __syncthreads();
        const float inv = 1.f / (red[4][i] + red[5][i] + red[6][i] + red[7][i]);
        #pragma unroll
        for (int jj = 0; jj < 16; ++jj) uv_smT[j0 + jj][i] = e[jj] * inv;
    }
    __syncthreads();

    {   // ypt[j][k] = sum_i c[j][i] x[k][i], 4j x 4k per thread, b128 reads
        const int a = tid & 15;
        const int kb = (tid >> 4) * 4;
        float acc[4][4] = {};
        for (int i = 0; i < ITILE; i += 4) {
            float4 xv[4];
            #pragma unroll
            for (int c = 0; c < 4; ++c) xv[c] = *(const float4*)&x_smT[kb + c][i];
            #pragma unroll
            for (int r = 0; r < 4; ++r) {
                const float4 cv = *(const float4*)&uv_smT[a + 16 * r][i];
                #pragma unroll
                for (int c = 0; c < 4; ++c)
                    acc[r][c] += cv.x * xv[c].x + cv.y * xv[c].y +
                                 cv.z * xv[c].z + cv.w * xv[c].w;
            }
        }
        #pragma unroll
        for (int r = 0; r < 4; ++r)
            *(float4*)&ypt[(a + 16 * r) * KK + kb] =
                make_float4(acc[r][0], acc[r][1], acc[r][2], acc[r][3]);
    }
}

// ---------------------------------------------------------------------------
// fused kernel. sync: cnt0[16] cnt0b[16] cnt1[16] cnt1b[16] cnt2[16]
//                     flag1[16] flag2[16]  (zeroed per launch)
// ---------------------------------------------------------------------------
__global__ __launch_bounds__(256, 2) void fused_kernel(
    const float* __restrict__ x, const float* __restrict__ W,
    float* __restrict__ wv, float* __restrict__ ypart,
    float* __restrict__ out, int* __restrict__ sync) {
    const int bid = blockIdx.x;
    const int b = bid >> 5;
    const int t = bid & 31;
    const int tid = threadIdx.x;

    int* cnt0  = sync;       int* cnt0b = sync + 16;
    int* cnt1  = sync + 32;  int* cnt1b = sync + 48;
    int* cnt2  = sync + 64;
    int* flag1 = sync + 80;  int* flag2 = sync + 96;

    float* wvb = wv + (size_t)b * JJ * KK;
    float* ypb = ypart + (size_t)b * NT * JJ * KK;   // ybar partials overlaid at ypb[0..2047]

    __shared__ alignas(16) float x_smT[KK][68];
    __shared__ alignas(16) float scratch[SCRATCH_FLOATS];
    __shared__ int role_sm;

    // ---- stage x tile (once, reused by ybar + both route passes) ----
    const float4* x4 = (const float4*)(x + ((size_t)b * II + t * ITILE) * KK);
    #pragma unroll
    for (int n = 0; n < 4; ++n) {
        const int idx = tid + n * 256;
        const int i = idx >> 4, kq = idx & 15;
        const float4 v = x4[idx];
        x_smT[kq * 4 + 0][i] = v.x;
        x_smT[kq * 4 + 1][i] = v.y;
        x_smT[kq * 4 + 2][i] = v.z;
        x_smT[kq * 4 + 3][i] = v.w;
    }
    __syncthreads();

    // ---- ybar partial: raw tile sum over 64 i ----
    {
        const int w = tid >> 6, lane = tid & 63;
        const int kk = lane >> 2, q = lane & 3;
        const int k = w * 16 + kk;
        float s = 0.f;
        #pragma unroll
        for (int m = 0; m < 4; ++m) {
            const float4 v = *(const float4*)&x_smT[k][q * 16 + m * 4];
            s += v.x + v.y + v.z + v.w;
        }
        s += __shfl_xor(s, 1, 64);
        s += __shfl_xor(s, 2, 64);
        if (q == 0) ypb[t * KK + k] = s;
    }
    __threadfence();
    __syncthreads();
    if (tid == 0)
        role_sm = __hip_atomic_fetch_add(&cnt0[b], 1, __ATOMIC_ACQ_REL, __HIP_MEMORY_SCOPE_AGENT);
    __syncthreads();
    const int r0 = role_sm;

    if (r0 >= NT - NCAPS) {
        while (__hip_atomic_load(&cnt0[b], __ATOMIC_RELAXED, __HIP_MEMORY_SCOPE_AGENT) < NT)
            __builtin_amdgcn_s_sleep(2);
        __threadfence();
        caps_tail<0>(b, r0 - (NT - NCAPS), W, ypb, wvb, out, scratch);
        __threadfence();
        __syncthreads();
        if (tid == 0 &&
            __hip_atomic_fetch_add(&cnt0b[b], 1, __ATOMIC_ACQ_REL, __HIP_MEMORY_SCOPE_AGENT) == NCAPS - 1)
            __hip_atomic_store(&flag1[b], 1, __ATOMIC_RELEASE, __HIP_MEMORY_SCOPE_AGENT);
    }
    while (__hip_atomic_load(&flag1[b], __ATOMIC_RELAXED, __HIP_MEMORY_SCOPE_AGENT) == 0)
        __builtin_amdgcn_s_sleep(8);
    __threadfence();

    route_pass(wvb, ypb + (size_t)t * JJ * KK, x_smT, scratch);   // pass 1

    __threadfence();
    __syncthreads();
    if (tid == 0)
        role_sm = __hip_atomic_fetch_add(&cnt1[b], 1, __ATOMIC_ACQ_REL, __HIP_MEMORY_SCOPE_AGENT);
    __syncthreads();
    const int r1 = role_sm;

    if (r1 >= NT - NCAPS) {
        while (__hip_atomic_load(&cnt1[b], __ATOMIC_RELAXED, __HIP_MEMORY_SCOPE_AGENT) < NT)
            __builtin_amdgcn_s_sleep(2);
        __threadfence();
        caps_tail<1>(b, r1 - (NT - NCAPS), W, ypb, wvb, out, scratch);
        __threadfence();
        __syncthreads();
        if (tid == 0 &&
            __hip_atomic_fetch_add(&cnt1b[b], 1, __ATOMIC_ACQ_REL, __HIP_MEMORY_SCOPE_AGENT) == NCAPS - 1)
            __hip_atomic_store(&flag2[b], 1, __ATOMIC_RELEASE, __HIP_MEMORY_SCOPE_AGENT);
    }
    while (__hip_atomic_load(&flag2[b], __ATOMIC_RELAXED, __HIP_MEMORY_SCOPE_AGENT) == 0)
        __builtin_amdgcn_s_sleep(8);
    __threadfence();

    route_pass(wvb, ypb + (size_t)t * JJ * KK, x_smT, scratch);   // pass 2

    __threadfence();
    __syncthreads();
    if (tid == 0)
        role_sm = __hip_atomic_fetch_add(&cnt2[b], 1, __ATOMIC_ACQ_REL, __HIP_MEMORY_SCOPE_AGENT);
    __syncthreads();
    const int r2 = role_sm;

    if (r2 >= NT - NCAPS) {
        while (__hip_atomic_load(&cnt2[b], __ATOMIC_RELAXED, __HIP_MEMORY_SCOPE_AGENT) < NT)
            __builtin_amdgcn_s_sleep(2);
        __threadfence();
        caps_tail<2>(b, r2 - (NT - NCAPS), W, ypb, wvb, out, scratch);
    }
}

// ---------------------------------------------------------------------------
// Workspace (floats): wv[65536] | ypart[2097152] | sync[112 ints]
// ybar partials live inside ypart[b] (dead before route1 overwrites them).
// ---------------------------------------------------------------------------
extern "C" void kernel_launch(void* const* d_in, const int* in_sizes, int n_in,
                              void* d_out, int out_size, void* d_ws, size_t ws_size,
                              hipStream_t stream) {
    (void)in_sizes; (void)n_in; (void)out_size; (void)ws_size;
    const float* x = (const float*)d_in[0];
    const float* W = (const float*)d_in[1];
    float* out = (float*)d_out;
    float* ws = (float*)d_ws;

    float* wv = ws;                         // 65536 floats
    float* ypart = ws + 65536;              // 2097152 floats
    int* sync = (int*)(ws + 65536 + 2097152);

    hipMemsetAsync(sync, 0, 112 * sizeof(int), stream);
    fused_kernel<<<dim3(BB * NT), dim3(256), 0, stream>>>(x, W, wv, ypart, out, sync);
}

// Round 3
// 561.586 us; speedup vs baseline: 1.0595x; 1.0595x over previous
//
#include <hip/hip_runtime.h>
#include <math.h>

// RoutingCapsules — B=16, I=2048, K=64, J=64, D=32, 3 routing iters.
//   s[b,j,d]  = sum_k W[j,d,k] y[b,j,k],    y[b,j,k]  = sum_i c[b,j,i] x[b,i,k]
//   uv[b,j,i] = sum_k x[b,i,k] wv[b,j,k],   wv[b,j,k] = sum_d W[j,d,k] v[b,j,d]
// Iter-1 c uniform -> y1 = (1/64) sum_i x.  Logits linear in wv -> wv2 = wv1+dwv.
//
// R4: fused single kernel as R3, but the sync layer rebuilt after the R3
// post-mortem (595us, VALUBusy 2.45% -> 97% of time spent spinning):
//  * every sync var padded to its own 256B line (was: all 112 ints in 1-2
//    cache lines shared by 512 blocks -> coherence-point queueing collapse)
//  * only wave 0 polls; waves 1-3 park at s_barrier (4x fewer spinners)
//  * s_sleep(16) backoff (~0.43us/poll; was s_sleep(2) ~ 128cy hammering)
// Contention per line: 512 blocks x 4 waves -> 32 blocks x 1 wave (~64x).

#define BB 16
#define II 2048
#define KK 64
#define JJ 64
#define DD 32
#define ITILE 64
#define NT 32              // i-tiles per b
#define NCAPS 8            // tail blocks per b doing caps
#define JPC (JJ / NCAPS)   // 8 j per caps block
#define JPW (JPC / 4)      // 2 j per wave

#define SCRATCH_FLOATS ((KK + JJ) * 68 + 8 * 72)   // 9280 floats = 37120 B

#define SYNC_STRIDE 64     // ints per sync var (256 B line each)
#define NSYNCVAR 7         // cnt0 cnt0b cnt1 cnt1b cnt2 flag1 flag2
#define SYNC_INTS (BB * NSYNCVAR * SYNC_STRIDE)

__device__ __forceinline__ int* svar(int* sync, int b, int v) {
    return sync + ((size_t)b * NSYNCVAR + v) * SYNC_STRIDE;
}

// wave-0-only poll until *p >= val, then release whole block with fresh caches
__device__ __forceinline__ void wait_ge(int* p, int val) {
    if (threadIdx.x < 64) {
        while (__hip_atomic_load(p, __ATOMIC_RELAXED, __HIP_MEMORY_SCOPE_AGENT) < val)
            __builtin_amdgcn_s_sleep(16);
    }
    __syncthreads();
    __threadfence();   // acquire: invalidate stale L1/L2 before reading payload
}

// ---------------------------------------------------------------------------
// caps tail: chunk of 8 j, 2 j per wave. Wave-private LDS (no syncthreads).
//   MODE 0: y = (1/64)*sum_t ybar-partials (j-indep); wv  = W^T v
//   MODE 1: y = sum_t ypart[t][j];                    wv += W^T v
//   MODE 2: y = sum_t ypart[t][j];                    out = squash(s)
// ---------------------------------------------------------------------------
template <int MODE>
__device__ __forceinline__ void caps_tail(int b, int chunk,
                                          const float* __restrict__ W,
                                          const float* __restrict__ ypb,
                                          float* __restrict__ wvb,
                                          float* __restrict__ out,
                                          float* scratch) {
    const int tid = threadIdx.x;
    const int w = tid >> 6, lane = tid & 63;
    float* W_sm = scratch + w * (DD * 68);                 // [32][68]
    float* y_sm = scratch + 4 * (DD * 68) + w * KK;        // [64]
    float* v_sm = scratch + 4 * (DD * 68) + 4 * KK + w * DD;

    if (MODE == 0) {   // y j-independent: compute once per wave
        const int kq = lane & 15, th = lane >> 4;
        float ax = 0.f, ay = 0.f, az = 0.f, aw = 0.f;
        #pragma unroll
        for (int n = 0; n < 8; ++n) {
            const float4 v = *(const float4*)(ypb + (th + n * 4) * KK + kq * 4);
            ax += v.x; ay += v.y; az += v.z; aw += v.w;
        }
        ax += __shfl_xor(ax, 16, 64); ay += __shfl_xor(ay, 16, 64);
        az += __shfl_xor(az, 16, 64); aw += __shfl_xor(aw, 16, 64);
        ax += __shfl_xor(ax, 32, 64); ay += __shfl_xor(ay, 32, 64);
        az += __shfl_xor(az, 32, 64); aw += __shfl_xor(aw, 32, 64);
        if (lane < 16)
            *(float4*)&y_sm[kq * 4] = make_float4(ax * (1.f / 64.f), ay * (1.f / 64.f),
                                                  az * (1.f / 64.f), aw * (1.f / 64.f));
    }

    #pragma unroll
    for (int jj = 0; jj < JPW; ++jj) {
        const int j = chunk * JPC + w * JPW + jj;
        const float* Wp = W + (size_t)j * DD * KK;
        #pragma unroll
        for (int rr = 0; rr < 8; ++rr) {
            const int idx = rr * 64 + lane;
            const int d = idx >> 4, kq = idx & 15;
            *(float4*)&W_sm[d * 68 + kq * 4] = *(const float4*)(Wp + d * KK + kq * 4);
        }
        if (MODE != 0) {   // y[j] = sum of 32 ypart tiles
            const int kq = lane & 15, th = lane >> 4;
            float ax = 0.f, ay = 0.f, az = 0.f, aw = 0.f;
            #pragma unroll
            for (int n = 0; n < 8; ++n) {
                const float4 v = *(const float4*)(ypb +
                    ((size_t)(th + n * 4) * JJ + j) * KK + kq * 4);
                ax += v.x; ay += v.y; az += v.z; aw += v.w;
            }
            ax += __shfl_xor(ax, 16, 64); ay += __shfl_xor(ay, 16, 64);
            az += __shfl_xor(az, 16, 64); aw += __shfl_xor(aw, 16, 64);
            ax += __shfl_xor(ax, 32, 64); ay += __shfl_xor(ay, 32, 64);
            az += __shfl_xor(az, 32, 64); aw += __shfl_xor(aw, 32, 64);
            if (lane < 16) *(float4*)&y_sm[kq * 4] = make_float4(ax, ay, az, aw);
        }

        // s[d] = sum_k W[d][k] y[k] — all 64 lanes: d=lane&31, k-half split
        const int d = lane & 31;
        const int kh = (lane >> 5) * 32;
        float sv = 0.f;
        #pragma unroll
        for (int kq = 0; kq < 8; ++kq) {
            const float4 wr = *(const float4*)&W_sm[d * 68 + kh + kq * 4];
            const float4 yr = *(const float4*)&y_sm[kh + kq * 4];
            sv += wr.x * yr.x + wr.y * yr.y + wr.z * yr.z + wr.w * yr.w;
        }
        sv += __shfl_xor(sv, 32, 64);
        float ps = sv * sv;
        #pragma unroll
        for (int m = 1; m < 32; m <<= 1) ps += __shfl_xor(ps, m, 64);
        const float f = ps / ((1.f + ps) * (sqrtf(ps) + 1e-8f));

        if (MODE == 2) {
            if (lane < DD) out[((size_t)b * JJ + j) * DD + lane] = sv * f;
        } else {
            if (lane < DD) v_sm[lane] = sv * f;
            float a = 0.f;
            #pragma unroll
            for (int dd = 0; dd < DD; ++dd) a += W_sm[dd * 68 + lane] * v_sm[dd];
            const size_t idx = (size_t)j * KK + lane;
            if (MODE == 1) a += wvb[idx];
            wvb[idx] = a;
        }
    }
}

// ---------------------------------------------------------------------------
// route pass: uv = x·wv^T; c = softmax_j; ypt[j][k] = sum_i c[j][i] x[k][i]
// ---------------------------------------------------------------------------
__device__ __forceinline__ void route_pass(const float* __restrict__ wvb,
                                           float* __restrict__ ypt,
                                           float (*x_smT)[68], float* scratch) {
    const int tid = threadIdx.x;
    float (*wv_smT)[68] = (float (*)[68])scratch;
    float (*uv_smT)[68] = (float (*)[68])(scratch + KK * 68);
    float (*red)[72]    = (float (*)[72])(scratch + (KK + JJ) * 68);

    const float4* wv4 = (const float4*)wvb;
    #pragma unroll
    for (int n = 0; n < 4; ++n) {
        const int idx = tid + n * 256;
        const int jj = idx >> 4, kq = idx & 15;
        const float4 v = wv4[idx];
        wv_smT[kq * 4 + 0][jj] = v.x;
        wv_smT[kq * 4 + 1][jj] = v.y;
        wv_smT[kq * 4 + 2][jj] = v.z;
        wv_smT[kq * 4 + 3][jj] = v.w;
    }
    __syncthreads();

    {   // uv[j][i], 4i x 4j per thread, b128 reads
        const int ib = (tid & 15) * 4, jb = (tid >> 4) * 4;
        float acc[4][4] = {};
        for (int k = 0; k < KK; ++k) {
            const float4 xv = *(const float4*)&x_smT[k][ib];
            const float4 wvv = *(const float4*)&wv_smT[k][jb];
            acc[0][0] += xv.x * wvv.x; acc[0][1] += xv.x * wvv.y;
            acc[0][2] += xv.x * wvv.z; acc[0][3] += xv.x * wvv.w;
            acc[1][0] += xv.y * wvv.x; acc[1][1] += xv.y * wvv.y;
            acc[1][2] += xv.y * wvv.z; acc[1][3] += xv.y * wvv.w;
            acc[2][0] += xv.z * wvv.x; acc[2][1] += xv.z * wvv.y;
            acc[2][2] += xv.z * wvv.z; acc[2][3] += xv.z * wvv.w;
            acc[3][0] += xv.w * wvv.x; acc[3][1] += xv.w * wvv.y;
            acc[3][2] += xv.w * wvv.z; acc[3][3] += xv.w * wvv.w;
        }
        #pragma unroll
        for (int r = 0; r < 4; ++r)
            *(float4*)&uv_smT[jb + r][ib] =
                make_float4(acc[0][r], acc[1][r], acc[2][r], acc[3][r]);
    }
    __syncthreads();

    {   // softmax over j (down columns); 16 values per wave in registers
        const int i = tid & 63;
        const int w = tid >> 6;
        const int j0 = w * 16;
        float e[16];
        float m = -1e30f;
        #pragma unroll
        for (int jj = 0; jj < 16; ++jj) {
            e[jj] = uv_smT[j0 + jj][i];
            m = fmaxf(m, e[jj]);
        }
        red[w][i] = m;
        __syncthreads();
        m = fmaxf(fmaxf(red[0][i], red[1][i]), fmaxf(red[2][i], red[3][i]));
        float s = 0.f;
        #pragma unroll
        for (int jj = 0; jj < 16; ++jj) {
            e[jj] = __expf(e[jj] - m);
            s += e[jj];
        }
        red[4 + w][i] = s;
        __syncthreads();
        const float inv = 1.f / (red[4][i] + red[5][i] + red[6][i] + red[7][i]);
        #pragma unroll
        for (int jj = 0; jj < 16; ++jj) uv_smT[j0 + jj][i] = e[jj] * inv;
    }
    __syncthreads();

    {   // ypt[j][k] = sum_i c[j][i] x[k][i], 4j x 4k per thread, b128 reads
        const int a = tid & 15;
        const int kb = (tid >> 4) * 4;
        float acc[4][4] = {};
        for (int i = 0; i < ITILE; i += 4) {
            float4 xv[4];
            #pragma unroll
            for (int c = 0; c < 4; ++c) xv[c] = *(const float4*)&x_smT[kb + c][i];
            #pragma unroll
            for (int r = 0; r < 4; ++r) {
                const float4 cv = *(const float4*)&uv_smT[a + 16 * r][i];
                #pragma unroll
                for (int c = 0; c < 4; ++c)
                    acc[r][c] += cv.x * xv[c].x + cv.y * xv[c].y +
                                 cv.z * xv[c].z + cv.w * xv[c].w;
            }
        }
        #pragma unroll
        for (int r = 0; r < 4; ++r)
            *(float4*)&ypt[(a + 16 * r) * KK + kb] =
                make_float4(acc[r][0], acc[r][1], acc[r][2], acc[r][3]);
    }
}

// ---------------------------------------------------------------------------
// fused kernel. sync vars per b: 0=cnt0 1=cnt0b 2=cnt1 3=cnt1b 4=cnt2
//                                5=flag1 6=flag2    (each on own 256B line)
// ---------------------------------------------------------------------------
__global__ __launch_bounds__(256, 2) void fused_kernel(
    const float* __restrict__ x, const float* __restrict__ W,
    float* __restrict__ wv, float* __restrict__ ypart,
    float* __restrict__ out, int* __restrict__ sync) {
    const int bid = blockIdx.x;
    const int b = bid >> 5;
    const int t = bid & 31;
    const int tid = threadIdx.x;

    int* cnt0  = svar(sync, b, 0);
    int* cnt0b = svar(sync, b, 1);
    int* cnt1  = svar(sync, b, 2);
    int* cnt1b = svar(sync, b, 3);
    int* cnt2  = svar(sync, b, 4);
    int* flag1 = svar(sync, b, 5);
    int* flag2 = svar(sync, b, 6);

    float* wvb = wv + (size_t)b * JJ * KK;
    float* ypb = ypart + (size_t)b * NT * JJ * KK;   // ybar partials overlaid at ypb[0..2047]

    __shared__ alignas(16) float x_smT[KK][68];
    __shared__ alignas(16) float scratch[SCRATCH_FLOATS];
    __shared__ int role_sm;

    // ---- stage x tile (once, reused by ybar + both route passes) ----
    const float4* x4 = (const float4*)(x + ((size_t)b * II + t * ITILE) * KK);
    #pragma unroll
    for (int n = 0; n < 4; ++n) {
        const int idx = tid + n * 256;
        const int i = idx >> 4, kq = idx & 15;
        const float4 v = x4[idx];
        x_smT[kq * 4 + 0][i] = v.x;
        x_smT[kq * 4 + 1][i] = v.y;
        x_smT[kq * 4 + 2][i] = v.z;
        x_smT[kq * 4 + 3][i] = v.w;
    }
    __syncthreads();

    // ---- ybar partial: raw tile sum over 64 i ----
    {
        const int w = tid >> 6, lane = tid & 63;
        const int kk = lane >> 2, q = lane & 3;
        const int k = w * 16 + kk;
        float s = 0.f;
        #pragma unroll
        for (int m = 0; m < 4; ++m) {
            const float4 v = *(const float4*)&x_smT[k][q * 16 + m * 4];
            s += v.x + v.y + v.z + v.w;
        }
        s += __shfl_xor(s, 1, 64);
        s += __shfl_xor(s, 2, 64);
        if (q == 0) ypb[t * KK + k] = s;
    }
    __threadfence();
    __syncthreads();
    if (tid == 0)
        role_sm = __hip_atomic_fetch_add(&cnt0[0], 1, __ATOMIC_ACQ_REL, __HIP_MEMORY_SCOPE_AGENT);
    __syncthreads();
    const int r0 = role_sm;

    if (r0 >= NT - NCAPS) {
        wait_ge(cnt0, NT);
        caps_tail<0>(b, r0 - (NT - NCAPS), W, ypb, wvb, out, scratch);
        __threadfence();
        __syncthreads();
        if (tid == 0 &&
            __hip_atomic_fetch_add(&cnt0b[0], 1, __ATOMIC_ACQ_REL, __HIP_MEMORY_SCOPE_AGENT) == NCAPS - 1)
            __hip_atomic_store(&flag1[0], 1, __ATOMIC_RELEASE, __HIP_MEMORY_SCOPE_AGENT);
    }
    wait_ge(flag1, 1);

    route_pass(wvb, ypb + (size_t)t * JJ * KK, x_smT, scratch);   // pass 1

    __threadfence();
    __syncthreads();
    if (tid == 0)
        role_sm = __hip_atomic_fetch_add(&cnt1[0], 1, __ATOMIC_ACQ_REL, __HIP_MEMORY_SCOPE_AGENT);
    __syncthreads();
    const int r1 = role_sm;

    if (r1 >= NT - NCAPS) {
        wait_ge(cnt1, NT);
        caps_tail<1>(b, r1 - (NT - NCAPS), W, ypb, wvb, out, scratch);
        __threadfence();
        __syncthreads();
        if (tid == 0 &&
            __hip_atomic_fetch_add(&cnt1b[0], 1, __ATOMIC_ACQ_REL, __HIP_MEMORY_SCOPE_AGENT) == NCAPS - 1)
            __hip_atomic_store(&flag2[0], 1, __ATOMIC_RELEASE, __HIP_MEMORY_SCOPE_AGENT);
    }
    wait_ge(flag2, 1);

    route_pass(wvb, ypb + (size_t)t * JJ * KK, x_smT, scratch);   // pass 2

    __threadfence();
    __syncthreads();
    if (tid == 0)
        role_sm = __hip_atomic_fetch_add(&cnt2[0], 1, __ATOMIC_ACQ_REL, __HIP_MEMORY_SCOPE_AGENT);
    __syncthreads();
    const int r2 = role_sm;

    if (r2 >= NT - NCAPS) {
        wait_ge(cnt2, NT);
        caps_tail<2>(b, r2 - (NT - NCAPS), W, ypb, wvb, out, scratch);
    }
}

// ---------------------------------------------------------------------------
// Workspace (floats): wv[65536] | ypart[2097152] | sync[7168 ints = 28KB]
// ybar partials live inside ypart[b] (dead before route1 overwrites them).
// ---------------------------------------------------------------------------
extern "C" void kernel_launch(void* const* d_in, const int* in_sizes, int n_in,
                              void* d_out, int out_size, void* d_ws, size_t ws_size,
                              hipStream_t stream) {
    (void)in_sizes; (void)n_in; (void)out_size; (void)ws_size;
    const float* x = (const float*)d_in[0];
    const float* W = (const float*)d_in[1];
    float* out = (float*)d_out;
    float* ws = (float*)d_ws;

    float* wv = ws;                         // 65536 floats
    float* ypart = ws + 65536;              // 2097152 floats
    int* sync = (int*)(ws + 65536 + 2097152);

    hipMemsetAsync(sync, 0, SYNC_INTS * sizeof(int), stream);
    fused_kernel<<<dim3(BB * NT), dim3(256), 0, stream>>>(x, W, wv, ypart, out, sync);
}

// Round 4
// 116.972 us; speedup vs baseline: 5.0867x; 4.8010x over previous
//
#include <hip/hip_runtime.h>
#include <math.h>

// RoutingCapsules — B=16, I=2048, K=64, J=64, D=32, 3 routing iters.
//   s[b,j,d]  = sum_k W[j,d,k] y[b,j,k],    y[b,j,k]  = sum_i c[b,j,i] x[b,i,k]
//   uv[b,j,i] = sum_k x[b,i,k] wv[b,j,k],   wv[b,j,k] = sum_d W[j,d,k] v[b,j,d]
// Iter-1 c uniform -> y1 = (1/64) sum_i x.  Logits linear in wv -> wv2 = wv1+dwv.
//
// R5: fused kernel, ZERO memory fences. R4 post-mortem: ~530us invariant to
// contention fixes; cause = ~20K per-wave __threadfence() calls, each a
// buffer_wbl2+buffer_inv (whole-XCD L2 writeback/invalidate) serializing on
// the 8 L2 engines. Fix: cross-block payload (ypart, wv, ybar partials) moves
// via relaxed AGENT-scope atomic load/store (sc0 sc1 -> coherence point;
// never dirty in L2, never stale in a cache). Ordering: __syncthreads()
// drains each wave's stores (vmcnt(0) before s_barrier), so a subsequent
// relaxed counter-add is globally ordered after the payload. x/W stay cached
// (read-only); out is flushed at kernel end.

#define BB 16
#define II 2048
#define KK 64
#define JJ 64
#define DD 32
#define ITILE 64
#define NT 32              // i-tiles per b
#define NCAPS 8            // tail blocks per b doing caps
#define JPC (JJ / NCAPS)   // 8 j per caps block
#define JPW (JPC / 4)      // 2 j per wave

#define SCRATCH_FLOATS ((KK + JJ) * 68 + 8 * 72)   // 9280 floats = 37120 B

#define SYNC_STRIDE 64     // ints per sync var (256 B line each)
#define NSYNCVAR 7
#define SYNC_INTS (BB * NSYNCVAR * SYNC_STRIDE)

__device__ __forceinline__ int* svar(int* sync, int b, int v) {
    return sync + ((size_t)b * NSYNCVAR + v) * SYNC_STRIDE;
}

// ---- coherent (cache-bypassing) payload accessors ----
__device__ __forceinline__ float cohload(const float* p) {
    return __hip_atomic_load(p, __ATOMIC_RELAXED, __HIP_MEMORY_SCOPE_AGENT);
}
__device__ __forceinline__ float4 cohload4(const float* p) {
    float4 v;
    v.x = cohload(p + 0); v.y = cohload(p + 1);
    v.z = cohload(p + 2); v.w = cohload(p + 3);
    return v;
}
__device__ __forceinline__ void cohstore(float* p, float v) {
    __hip_atomic_store(p, v, __ATOMIC_RELAXED, __HIP_MEMORY_SCOPE_AGENT);
}
__device__ __forceinline__ void cohstore4(float* p, float4 v) {
    cohstore(p + 0, v.x); cohstore(p + 1, v.y);
    cohstore(p + 2, v.z); cohstore(p + 3, v.w);
}

// wave-0 spin until *p >= val, then release block. No fence needed: payload
// never lives in a cache.
__device__ __forceinline__ void wait_ge(int* p, int val) {
    if (threadIdx.x < 64) {
        while (__hip_atomic_load(p, __ATOMIC_RELAXED, __HIP_MEMORY_SCOPE_AGENT) < val)
            __builtin_amdgcn_s_sleep(8);
    }
    __syncthreads();
}

// ---------------------------------------------------------------------------
// caps tail: chunk of 8 j, 2 j per wave. Wave-private LDS (no syncthreads).
//   MODE 0: y = (1/64)*sum_t ybar-partials (j-indep); wv  = W^T v
//   MODE 1: y = sum_t ypart[t][j];                    wv += W^T v
//   MODE 2: y = sum_t ypart[t][j];                    out = squash(s)
// ---------------------------------------------------------------------------
template <int MODE>
__device__ __forceinline__ void caps_tail(int b, int chunk,
                                          const float* __restrict__ W,
                                          const float* __restrict__ ypb,
                                          float* __restrict__ wvb,
                                          float* __restrict__ out,
                                          float* scratch) {
    const int tid = threadIdx.x;
    const int w = tid >> 6, lane = tid & 63;
    float* W_sm = scratch + w * (DD * 68);                 // [32][68]
    float* y_sm = scratch + 4 * (DD * 68) + w * KK;        // [64]
    float* v_sm = scratch + 4 * (DD * 68) + 4 * KK + w * DD;

    if (MODE == 0) {   // y j-independent: compute once per wave
        const int kq = lane & 15, th = lane >> 4;
        float ax = 0.f, ay = 0.f, az = 0.f, aw = 0.f;
        #pragma unroll
        for (int n = 0; n < 8; ++n) {
            const float4 v = cohload4(ypb + (th + n * 4) * KK + kq * 4);
            ax += v.x; ay += v.y; az += v.z; aw += v.w;
        }
        ax += __shfl_xor(ax, 16, 64); ay += __shfl_xor(ay, 16, 64);
        az += __shfl_xor(az, 16, 64); aw += __shfl_xor(aw, 16, 64);
        ax += __shfl_xor(ax, 32, 64); ay += __shfl_xor(ay, 32, 64);
        az += __shfl_xor(az, 32, 64); aw += __shfl_xor(aw, 32, 64);
        if (lane < 16)
            *(float4*)&y_sm[kq * 4] = make_float4(ax * (1.f / 64.f), ay * (1.f / 64.f),
                                                  az * (1.f / 64.f), aw * (1.f / 64.f));
    }

    #pragma unroll
    for (int jj = 0; jj < JPW; ++jj) {
        const int j = chunk * JPC + w * JPW + jj;
        const float* Wp = W + (size_t)j * DD * KK;
        #pragma unroll
        for (int rr = 0; rr < 8; ++rr) {
            const int idx = rr * 64 + lane;
            const int d = idx >> 4, kq = idx & 15;
            *(float4*)&W_sm[d * 68 + kq * 4] = *(const float4*)(Wp + d * KK + kq * 4);
        }
        if (MODE != 0) {   // y[j] = sum of 32 ypart tiles
            const int kq = lane & 15, th = lane >> 4;
            float ax = 0.f, ay = 0.f, az = 0.f, aw = 0.f;
            #pragma unroll
            for (int n = 0; n < 8; ++n) {
                const float4 v = cohload4(ypb +
                    ((size_t)(th + n * 4) * JJ + j) * KK + kq * 4);
                ax += v.x; ay += v.y; az += v.z; aw += v.w;
            }
            ax += __shfl_xor(ax, 16, 64); ay += __shfl_xor(ay, 16, 64);
            az += __shfl_xor(az, 16, 64); aw += __shfl_xor(aw, 16, 64);
            ax += __shfl_xor(ax, 32, 64); ay += __shfl_xor(ay, 32, 64);
            az += __shfl_xor(az, 32, 64); aw += __shfl_xor(aw, 32, 64);
            if (lane < 16) *(float4*)&y_sm[kq * 4] = make_float4(ax, ay, az, aw);
        }

        // s[d] = sum_k W[d][k] y[k] — all 64 lanes: d=lane&31, k-half split
        const int d = lane & 31;
        const int kh = (lane >> 5) * 32;
        float sv = 0.f;
        #pragma unroll
        for (int kq = 0; kq < 8; ++kq) {
            const float4 wr = *(const float4*)&W_sm[d * 68 + kh + kq * 4];
            const float4 yr = *(const float4*)&y_sm[kh + kq * 4];
            sv += wr.x * yr.x + wr.y * yr.y + wr.z * yr.z + wr.w * yr.w;
        }
        sv += __shfl_xor(sv, 32, 64);
        float ps = sv * sv;
        #pragma unroll
        for (int m = 1; m < 32; m <<= 1) ps += __shfl_xor(ps, m, 64);
        const float f = ps / ((1.f + ps) * (sqrtf(ps) + 1e-8f));

        if (MODE == 2) {
            if (lane < DD) out[((size_t)b * JJ + j) * DD + lane] = sv * f;
        } else {
            if (lane < DD) v_sm[lane] = sv * f;
            float a = 0.f;
            #pragma unroll
            for (int dd = 0; dd < DD; ++dd) a += W_sm[dd * 68 + lane] * v_sm[dd];
            const size_t idx = (size_t)j * KK + lane;
            if (MODE == 1) a += cohload(wvb + idx);
            cohstore(wvb + idx, a);
        }
    }
}

// ---------------------------------------------------------------------------
// route pass: uv = x·wv^T; c = softmax_j; ypt[j][k] = sum_i c[j][i] x[k][i]
// ---------------------------------------------------------------------------
__device__ __forceinline__ void route_pass(const float* __restrict__ wvb,
                                           float* __restrict__ ypt,
                                           float (*x_smT)[68], float* scratch) {
    const int tid = threadIdx.x;
    float (*wv_smT)[68] = (float (*)[68])scratch;
    float (*uv_smT)[68] = (float (*)[68])(scratch + KK * 68);
    float (*red)[72]    = (float (*)[72])(scratch + (KK + JJ) * 68);

    #pragma unroll
    for (int n = 0; n < 4; ++n) {
        const int idx = tid + n * 256;
        const int jj = idx >> 4, kq = idx & 15;
        const float4 v = cohload4(wvb + idx * 4);
        wv_smT[kq * 4 + 0][jj] = v.x;
        wv_smT[kq * 4 + 1][jj] = v.y;
        wv_smT[kq * 4 + 2][jj] = v.z;
        wv_smT[kq * 4 + 3][jj] = v.w;
    }
    __syncthreads();

    {   // uv[j][i], 4i x 4j per thread, b128 reads
        const int ib = (tid & 15) * 4, jb = (tid >> 4) * 4;
        float acc[4][4] = {};
        for (int k = 0; k < KK; ++k) {
            const float4 xv = *(const float4*)&x_smT[k][ib];
            const float4 wvv = *(const float4*)&wv_smT[k][jb];
            acc[0][0] += xv.x * wvv.x; acc[0][1] += xv.x * wvv.y;
            acc[0][2] += xv.x * wvv.z; acc[0][3] += xv.x * wvv.w;
            acc[1][0] += xv.y * wvv.x; acc[1][1] += xv.y * wvv.y;
            acc[1][2] += xv.y * wvv.z; acc[1][3] += xv.y * wvv.w;
            acc[2][0] += xv.z * wvv.x; acc[2][1] += xv.z * wvv.y;
            acc[2][2] += xv.z * wvv.z; acc[2][3] += xv.z * wvv.w;
            acc[3][0] += xv.w * wvv.x; acc[3][1] += xv.w * wvv.y;
            acc[3][2] += xv.w * wvv.z; acc[3][3] += xv.w * wvv.w;
        }
        #pragma unroll
        for (int r = 0; r < 4; ++r)
            *(float4*)&uv_smT[jb + r][ib] =
                make_float4(acc[0][r], acc[1][r], acc[2][r], acc[3][r]);
    }
    __syncthreads();

    {   // softmax over j (down columns); 16 values per wave in registers
        const int i = tid & 63;
        const int w = tid >> 6;
        const int j0 = w * 16;
        float e[16];
        float m = -1e30f;
        #pragma unroll
        for (int jj = 0; jj < 16; ++jj) {
            e[jj] = uv_smT[j0 + jj][i];
            m = fmaxf(m, e[jj]);
        }
        red[w][i] = m;
        __syncthreads();
        m = fmaxf(fmaxf(red[0][i], red[1][i]), fmaxf(red[2][i], red[3][i]));
        float s = 0.f;
        #pragma unroll
        for (int jj = 0; jj < 16; ++jj) {
            e[jj] = __expf(e[jj] - m);
            s += e[jj];
        }
        red[4 + w][i] = s;
        __syncthreads();
        const float inv = 1.f / (red[4][i] + red[5][i] + red[6][i] + red[7][i]);
        #pragma unroll
        for (int jj = 0; jj < 16; ++jj) uv_smT[j0 + jj][i] = e[jj] * inv;
    }
    __syncthreads();

    {   // ypt[j][k] = sum_i c[j][i] x[k][i], 4j x 4k per thread, b128 reads
        const int a = tid & 15;
        const int kb = (tid >> 4) * 4;
        float acc[4][4] = {};
        for (int i = 0; i < ITILE; i += 4) {
            float4 xv[4];
            #pragma unroll
            for (int c = 0; c < 4; ++c) xv[c] = *(const float4*)&x_smT[kb + c][i];
            #pragma unroll
            for (int r = 0; r < 4; ++r) {
                const float4 cv = *(const float4*)&uv_smT[a + 16 * r][i];
                #pragma unroll
                for (int c = 0; c < 4; ++c)
                    acc[r][c] += cv.x * xv[c].x + cv.y * xv[c].y +
                                 cv.z * xv[c].z + cv.w * xv[c].w;
            }
        }
        #pragma unroll
        for (int r = 0; r < 4; ++r)
            cohstore4(&ypt[(a + 16 * r) * KK + kb],
                      make_float4(acc[r][0], acc[r][1], acc[r][2], acc[r][3]));
    }
}

// ---------------------------------------------------------------------------
// fused kernel. sync vars per b: 0=cnt0 1=cnt0b 2=cnt1 3=cnt1b 4=cnt2
//                                5=flag1 6=flag2    (each on own 256B line)
// ---------------------------------------------------------------------------
__global__ __launch_bounds__(256, 2) void fused_kernel(
    const float* __restrict__ x, const float* __restrict__ W,
    float* __restrict__ wv, float* __restrict__ ypart,
    float* __restrict__ out, int* __restrict__ sync) {
    const int bid = blockIdx.x;
    const int b = bid >> 5;
    const int t = bid & 31;
    const int tid = threadIdx.x;

    int* cnt0  = svar(sync, b, 0);
    int* cnt0b = svar(sync, b, 1);
    int* cnt1  = svar(sync, b, 2);
    int* cnt1b = svar(sync, b, 3);
    int* cnt2  = svar(sync, b, 4);
    int* flag1 = svar(sync, b, 5);
    int* flag2 = svar(sync, b, 6);

    float* wvb = wv + (size_t)b * JJ * KK;
    float* ypb = ypart + (size_t)b * NT * JJ * KK;   // ybar partials overlaid at ypb[0..2047]

    __shared__ alignas(16) float x_smT[KK][68];
    __shared__ alignas(16) float scratch[SCRATCH_FLOATS];
    __shared__ int role_sm;

    // ---- stage x tile (once, reused by ybar + both route passes) ----
    const float4* x4 = (const float4*)(x + ((size_t)b * II + t * ITILE) * KK);
    #pragma unroll
    for (int n = 0; n < 4; ++n) {
        const int idx = tid + n * 256;
        const int i = idx >> 4, kq = idx & 15;
        const float4 v = x4[idx];
        x_smT[kq * 4 + 0][i] = v.x;
        x_smT[kq * 4 + 1][i] = v.y;
        x_smT[kq * 4 + 2][i] = v.z;
        x_smT[kq * 4 + 3][i] = v.w;
    }
    __syncthreads();

    // ---- ybar partial: raw tile sum over 64 i ----
    {
        const int w = tid >> 6, lane = tid & 63;
        const int kk = lane >> 2, q = lane & 3;
        const int k = w * 16 + kk;
        float s = 0.f;
        #pragma unroll
        for (int m = 0; m < 4; ++m) {
            const float4 v = *(const float4*)&x_smT[k][q * 16 + m * 4];
            s += v.x + v.y + v.z + v.w;
        }
        s += __shfl_xor(s, 1, 64);
        s += __shfl_xor(s, 2, 64);
        if (q == 0) cohstore(&ypb[t * KK + k], s);
    }
    __syncthreads();   // drains all waves' stores (vmcnt(0) before s_barrier)
    if (tid == 0)
        role_sm = __hip_atomic_fetch_add(&cnt0[0], 1, __ATOMIC_RELAXED, __HIP_MEMORY_SCOPE_AGENT);
    __syncthreads();
    const int r0 = role_sm;

    if (r0 >= NT - NCAPS) {
        wait_ge(cnt0, NT);
        caps_tail<0>(b, r0 - (NT - NCAPS), W, ypb, wvb, out, scratch);
        __syncthreads();
        if (tid == 0 &&
            __hip_atomic_fetch_add(&cnt0b[0], 1, __ATOMIC_RELAXED, __HIP_MEMORY_SCOPE_AGENT) == NCAPS - 1)
            __hip_atomic_store(&flag1[0], 1, __ATOMIC_RELAXED, __HIP_MEMORY_SCOPE_AGENT);
    }
    wait_ge(flag1, 1);

    route_pass(wvb, ypb + (size_t)t * JJ * KK, x_smT, scratch);   // pass 1

    __syncthreads();
    if (tid == 0)
        role_sm = __hip_atomic_fetch_add(&cnt1[0], 1, __ATOMIC_RELAXED, __HIP_MEMORY_SCOPE_AGENT);
    __syncthreads();
    const int r1 = role_sm;

    if (r1 >= NT - NCAPS) {
        wait_ge(cnt1, NT);
        caps_tail<1>(b, r1 - (NT - NCAPS), W, ypb, wvb, out, scratch);
        __syncthreads();
        if (tid == 0 &&
            __hip_atomic_fetch_add(&cnt1b[0], 1, __ATOMIC_RELAXED, __HIP_MEMORY_SCOPE_AGENT) == NCAPS - 1)
            __hip_atomic_store(&flag2[0], 1, __ATOMIC_RELAXED, __HIP_MEMORY_SCOPE_AGENT);
    }
    wait_ge(flag2, 1);

    route_pass(wvb, ypb + (size_t)t * JJ * KK, x_smT, scratch);   // pass 2

    __syncthreads();
    if (tid == 0)
        role_sm = __hip_atomic_fetch_add(&cnt2[0], 1, __ATOMIC_RELAXED, __HIP_MEMORY_SCOPE_AGENT);
    __syncthreads();
    const int r2 = role_sm;

    if (r2 >= NT - NCAPS) {
        wait_ge(cnt2, NT);
        caps_tail<2>(b, r2 - (NT - NCAPS), W, ypb, wvb, out, scratch);
    }
}

// ---------------------------------------------------------------------------
// Workspace (floats): wv[65536] | ypart[2097152] | sync[7168 ints = 28KB]
// ybar partials live inside ypart[b] (dead before route1 overwrites them).
// ---------------------------------------------------------------------------
extern "C" void kernel_launch(void* const* d_in, const int* in_sizes, int n_in,
                              void* d_out, int out_size, void* d_ws, size_t ws_size,
                              hipStream_t stream) {
    (void)in_sizes; (void)n_in; (void)out_size; (void)ws_size;
    const float* x = (const float*)d_in[0];
    const float* W = (const float*)d_in[1];
    float* out = (float*)d_out;
    float* ws = (float*)d_ws;

    float* wv = ws;                         // 65536 floats
    float* ypart = ws + 65536;              // 2097152 floats
    int* sync = (int*)(ws + 65536 + 2097152);

    hipMemsetAsync(sync, 0, SYNC_INTS * sizeof(int), stream);
    fused_kernel<<<dim3(BB * NT), dim3(256), 0, stream>>>(x, W, wv, ypart, out, sync);
}

// Round 5
// 100.284 us; speedup vs baseline: 5.9331x; 1.1664x over previous
//
#include <hip/hip_runtime.h>
#include <math.h>

// RoutingCapsules — B=16, I=2048, K=64, J=64, D=32, 3 routing iters.
//   s[b,j,d]  = sum_k W[j,d,k] y[b,j,k],    y[b,j,k]  = sum_i c[b,j,i] x[b,i,k]
//   uv[b,j,i] = sum_k x[b,i,k] wv[b,j,k],   wv[b,j,k] = sum_d W[j,d,k] v[b,j,d]
// Iter-1 c uniform -> y1 = (1/64) sum_i x.  Logits linear in wv -> wv2 = wv1+dwv.
//
// R6: fused, zero-fence (R5 design), but cross-block payload moves via
// 16-BYTE inline-asm sc0 sc1 accesses instead of scalar __hip_atomic dwords.
// R5 post-mortem: dword write-through to 256B-strided rows moved a 64B line
// per 16B stored -> WRITE_SIZE 17->66MB and 4x VMEM issue. dwordx4 stores
// form full 64B lines per wave; loads batch-issue then wait once
// (s_waitcnt vmcnt(0) + sched_barrier(0) per guide rule #18).

#define BB 16
#define II 2048
#define KK 64
#define JJ 64
#define DD 32
#define ITILE 64
#define NT 32              // i-tiles per b
#define NCAPS 8            // tail blocks per b doing caps
#define JPC (JJ / NCAPS)   // 8 j per caps block
#define JPW (JPC / 4)      // 2 j per wave

#define SCRATCH_FLOATS ((KK + JJ) * 68 + 8 * 72)   // 9280 floats = 37120 B

#define SYNC_STRIDE 64     // ints per sync var (256 B line each)
#define NSYNCVAR 7
#define SYNC_INTS (BB * NSYNCVAR * SYNC_STRIDE)

typedef float f32x4 __attribute__((ext_vector_type(4)));

__device__ __forceinline__ int* svar(int* sync, int b, int v) {
    return sync + ((size_t)b * NSYNCVAR + v) * SYNC_STRIDE;
}

// ---- coherent (cache-bypassing) payload accessors, 16B-wide, async ----
// Values returned by *_a loads are UNDEFINED until cohwait0() runs.
__device__ __forceinline__ f32x4 cohload4a(const float* p) {
    f32x4 t;
    asm volatile("global_load_dwordx4 %0, %1, off sc0 sc1"
                 : "=&v"(t) : "v"(p) : "memory");
    return t;
}
__device__ __forceinline__ float cohload1a(const float* p) {
    float t;
    asm volatile("global_load_dword %0, %1, off sc0 sc1"
                 : "=&v"(t) : "v"(p) : "memory");
    return t;
}
__device__ __forceinline__ void cohwait0() {
    asm volatile("s_waitcnt vmcnt(0)" ::: "memory");
    __builtin_amdgcn_sched_barrier(0);   // rule #18: pin uses after the wait
}
__device__ __forceinline__ void cohstore4(float* p, f32x4 v) {
    asm volatile("global_store_dwordx4 %0, %1, off sc0 sc1"
                 :: "v"(p), "v"(v) : "memory");
}
__device__ __forceinline__ void cohstore1(float* p, float v) {
    asm volatile("global_store_dword %0, %1, off sc0 sc1"
                 :: "v"(p), "v"(v) : "memory");
}
// drain our asm stores before a counter add becomes visible
__device__ __forceinline__ void cohfence() {
    asm volatile("s_waitcnt vmcnt(0)" ::: "memory");
}

// wave-0 spin until *p >= val, then release block (payload never cached)
__device__ __forceinline__ void wait_ge(int* p, int val) {
    if (threadIdx.x < 64) {
        while (__hip_atomic_load(p, __ATOMIC_RELAXED, __HIP_MEMORY_SCOPE_AGENT) < val)
            __builtin_amdgcn_s_sleep(8);
    }
    __syncthreads();
}

// ---------------------------------------------------------------------------
// caps tail: chunk of 8 j, 2 j per wave. Wave-private LDS (no syncthreads).
//   MODE 0: y = (1/64)*sum_t ybar-partials (j-indep); wv  = W^T v
//   MODE 1: y = sum_t ypart[t][j];                    wv += W^T v
//   MODE 2: y = sum_t ypart[t][j];                    out = squash(s)
// ---------------------------------------------------------------------------
template <int MODE>
__device__ __forceinline__ void caps_tail(int b, int chunk,
                                          const float* __restrict__ W,
                                          const float* __restrict__ ypb,
                                          float* __restrict__ wvb,
                                          float* __restrict__ out,
                                          float* scratch) {
    const int tid = threadIdx.x;
    const int w = tid >> 6, lane = tid & 63;
    float* W_sm = scratch + w * (DD * 68);                 // [32][68]
    float* y_sm = scratch + 4 * (DD * 68) + w * KK;        // [64]
    float* v_sm = scratch + 4 * (DD * 68) + 4 * KK + w * DD;
    const int kq = lane & 15, th = lane >> 4;

    if (MODE == 0) {   // y j-independent: compute once per wave
        f32x4 vb[8];
        #pragma unroll
        for (int n = 0; n < 8; ++n)
            vb[n] = cohload4a(ypb + (th + n * 4) * KK + kq * 4);
        cohwait0();
        float ax = 0.f, ay = 0.f, az = 0.f, aw = 0.f;
        #pragma unroll
        for (int n = 0; n < 8; ++n) {
            ax += vb[n][0]; ay += vb[n][1]; az += vb[n][2]; aw += vb[n][3];
        }
        ax += __shfl_xor(ax, 16, 64); ay += __shfl_xor(ay, 16, 64);
        az += __shfl_xor(az, 16, 64); aw += __shfl_xor(aw, 16, 64);
        ax += __shfl_xor(ax, 32, 64); ay += __shfl_xor(ay, 32, 64);
        az += __shfl_xor(az, 32, 64); aw += __shfl_xor(aw, 32, 64);
        if (lane < 16)
            *(float4*)&y_sm[kq * 4] = make_float4(ax * (1.f / 64.f), ay * (1.f / 64.f),
                                                  az * (1.f / 64.f), aw * (1.f / 64.f));
    }

    #pragma unroll
    for (int jj = 0; jj < JPW; ++jj) {
        const int j = chunk * JPC + w * JPW + jj;
        const float* Wp = W + (size_t)j * DD * KK;
        #pragma unroll
        for (int rr = 0; rr < 8; ++rr) {
            const int idx = rr * 64 + lane;
            const int d = idx >> 4, kq2 = idx & 15;
            *(float4*)&W_sm[d * 68 + kq2 * 4] = *(const float4*)(Wp + d * KK + kq2 * 4);
        }

        const size_t widx = (size_t)j * KK + lane;
        float wvold = 0.f;
        if (MODE != 0) {   // y[j] = sum of 32 ypart tiles (batched async loads)
            f32x4 vb[8];
            #pragma unroll
            for (int n = 0; n < 8; ++n)
                vb[n] = cohload4a(ypb + ((size_t)(th + n * 4) * JJ + j) * KK + kq * 4);
            if (MODE == 1) wvold = cohload1a(wvb + widx);
            cohwait0();
            float ax = 0.f, ay = 0.f, az = 0.f, aw = 0.f;
            #pragma unroll
            for (int n = 0; n < 8; ++n) {
                ax += vb[n][0]; ay += vb[n][1]; az += vb[n][2]; aw += vb[n][3];
            }
            ax += __shfl_xor(ax, 16, 64); ay += __shfl_xor(ay, 16, 64);
            az += __shfl_xor(az, 16, 64); aw += __shfl_xor(aw, 16, 64);
            ax += __shfl_xor(ax, 32, 64); ay += __shfl_xor(ay, 32, 64);
            az += __shfl_xor(az, 32, 64); aw += __shfl_xor(aw, 32, 64);
            if (lane < 16) *(float4*)&y_sm[kq * 4] = make_float4(ax, ay, az, aw);
        }

        // s[d] = sum_k W[d][k] y[k] — all 64 lanes: d=lane&31, k-half split
        const int d = lane & 31;
        const int kh = (lane >> 5) * 32;
        float sv = 0.f;
        #pragma unroll
        for (int kk2 = 0; kk2 < 8; ++kk2) {
            const float4 wr = *(const float4*)&W_sm[d * 68 + kh + kk2 * 4];
            const float4 yr = *(const float4*)&y_sm[kh + kk2 * 4];
            sv += wr.x * yr.x + wr.y * yr.y + wr.z * yr.z + wr.w * yr.w;
        }
        sv += __shfl_xor(sv, 32, 64);
        float ps = sv * sv;
        #pragma unroll
        for (int m = 1; m < 32; m <<= 1) ps += __shfl_xor(ps, m, 64);
        const float f = ps / ((1.f + ps) * (sqrtf(ps) + 1e-8f));

        if (MODE == 2) {
            if (lane < DD) out[((size_t)b * JJ + j) * DD + lane] = sv * f;
        } else {
            if (lane < DD) v_sm[lane] = sv * f;
            float a = 0.f;
            #pragma unroll
            for (int dd = 0; dd < DD; ++dd) a += W_sm[dd * 68 + lane] * v_sm[dd];
            if (MODE == 1) a += wvold;
            cohstore1(wvb + widx, a);
        }
    }
}

// ---------------------------------------------------------------------------
// route pass: uv = x·wv^T; c = softmax_j; ypt[j][k] = sum_i c[j][i] x[k][i]
// ---------------------------------------------------------------------------
__device__ __forceinline__ void route_pass(const float* __restrict__ wvb,
                                           float* __restrict__ ypt,
                                           float (*x_smT)[68], float* scratch) {
    const int tid = threadIdx.x;
    float (*wv_smT)[68] = (float (*)[68])scratch;
    float (*uv_smT)[68] = (float (*)[68])(scratch + KK * 68);
    float (*red)[72]    = (float (*)[72])(scratch + (KK + JJ) * 68);

    {   // stage wv (transposed) — batched async coherent 16B loads
        f32x4 vb[4];
        #pragma unroll
        for (int n = 0; n < 4; ++n)
            vb[n] = cohload4a(wvb + (size_t)(tid + n * 256) * 4);
        cohwait0();
        #pragma unroll
        for (int n = 0; n < 4; ++n) {
            const int idx = tid + n * 256;
            const int jj = idx >> 4, kq = idx & 15;
            wv_smT[kq * 4 + 0][jj] = vb[n][0];
            wv_smT[kq * 4 + 1][jj] = vb[n][1];
            wv_smT[kq * 4 + 2][jj] = vb[n][2];
            wv_smT[kq * 4 + 3][jj] = vb[n][3];
        }
    }
    __syncthreads();

    {   // uv[j][i], 4i x 4j per thread, b128 reads
        const int ib = (tid & 15) * 4, jb = (tid >> 4) * 4;
        float acc[4][4] = {};
        for (int k = 0; k < KK; ++k) {
            const float4 xv = *(const float4*)&x_smT[k][ib];
            const float4 wvv = *(const float4*)&wv_smT[k][jb];
            acc[0][0] += xv.x * wvv.x; acc[0][1] += xv.x * wvv.y;
            acc[0][2] += xv.x * wvv.z; acc[0][3] += xv.x * wvv.w;
            acc[1][0] += xv.y * wvv.x; acc[1][1] += xv.y * wvv.y;
            acc[1][2] += xv.y * wvv.z; acc[1][3] += xv.y * wvv.w;
            acc[2][0] += xv.z * wvv.x; acc[2][1] += xv.z * wvv.y;
            acc[2][2] += xv.z * wvv.z; acc[2][3] += xv.z * wvv.w;
            acc[3][0] += xv.w * wvv.x; acc[3][1] += xv.w * wvv.y;
            acc[3][2] += xv.w * wvv.z; acc[3][3] += xv.w * wvv.w;
        }
        #pragma unroll
        for (int r = 0; r < 4; ++r)
            *(float4*)&uv_smT[jb + r][ib] =
                make_float4(acc[0][r], acc[1][r], acc[2][r], acc[3][r]);
    }
    __syncthreads();

    {   // softmax over j (down columns); 16 values per wave in registers
        const int i = tid & 63;
        const int w = tid >> 6;
        const int j0 = w * 16;
        float e[16];
        float m = -1e30f;
        #pragma unroll
        for (int jj = 0; jj < 16; ++jj) {
            e[jj] = uv_smT[j0 + jj][i];
            m = fmaxf(m, e[jj]);
        }
        red[w][i] = m;
        __syncthreads();
        m = fmaxf(fmaxf(red[0][i], red[1][i]), fmaxf(red[2][i], red[3][i]));
        float s = 0.f;
        #pragma unroll
        for (int jj = 0; jj < 16; ++jj) {
            e[jj] = __expf(e[jj] - m);
            s += e[jj];
        }
        red[4 + w][i] = s;
        __syncthreads();
        const float inv = 1.f / (red[4][i] + red[5][i] + red[6][i] + red[7][i]);
        #pragma unroll
        for (int jj = 0; jj < 16; ++jj) uv_smT[j0 + jj][i] = e[jj] * inv;
    }
    __syncthreads();

    {   // ypt[j][k] = sum_i c[j][i] x[k][i], 4j x 4k per thread, b128 reads.
        // Per wave, rows a+16r are written by 4 lanes x 16B contiguous = full
        // 64B lines -> no write-through inflation.
        const int a = tid & 15;
        const int kb = (tid >> 4) * 4;
        float acc[4][4] = {};
        for (int i = 0; i < ITILE; i += 4) {
            float4 xv[4];
            #pragma unroll
            for (int c = 0; c < 4; ++c) xv[c] = *(const float4*)&x_smT[kb + c][i];
            #pragma unroll
            for (int r = 0; r < 4; ++r) {
                const float4 cv = *(const float4*)&uv_smT[a + 16 * r][i];
                #pragma unroll
                for (int c = 0; c < 4; ++c)
                    acc[r][c] += cv.x * xv[c].x + cv.y * xv[c].y +
                                 cv.z * xv[c].z + cv.w * xv[c].w;
            }
        }
        #pragma unroll
        for (int r = 0; r < 4; ++r) {
            f32x4 sv;
            sv[0] = acc[r][0]; sv[1] = acc[r][1]; sv[2] = acc[r][2]; sv[3] = acc[r][3];
            cohstore4(&ypt[(a + 16 * r) * KK + kb], sv);
        }
    }
}

// ---------------------------------------------------------------------------
// fused kernel. sync vars per b: 0=cnt0 1=cnt0b 2=cnt1 3=cnt1b 4=cnt2
//                                5=flag1 6=flag2    (each on own 256B line)
// ---------------------------------------------------------------------------
__global__ __launch_bounds__(256, 2) void fused_kernel(
    const float* __restrict__ x, const float* __restrict__ W,
    float* __restrict__ wv, float* __restrict__ ypart,
    float* __restrict__ out, int* __restrict__ sync) {
    const int bid = blockIdx.x;
    const int b = bid >> 5;
    const int t = bid & 31;
    const int tid = threadIdx.x;

    int* cnt0  = svar(sync, b, 0);
    int* cnt0b = svar(sync, b, 1);
    int* cnt1  = svar(sync, b, 2);
    int* cnt1b = svar(sync, b, 3);
    int* cnt2  = svar(sync, b, 4);
    int* flag1 = svar(sync, b, 5);
    int* flag2 = svar(sync, b, 6);

    float* wvb = wv + (size_t)b * JJ * KK;
    float* ypb = ypart + (size_t)b * NT * JJ * KK;   // ybar partials overlaid at ypb[0..2047]

    __shared__ alignas(16) float x_smT[KK][68];
    __shared__ alignas(16) float scratch[SCRATCH_FLOATS];
    __shared__ int role_sm;

    // ---- stage x tile (once, reused by ybar + both route passes) ----
    const float4* x4 = (const float4*)(x + ((size_t)b * II + t * ITILE) * KK);
    #pragma unroll
    for (int n = 0; n < 4; ++n) {
        const int idx = tid + n * 256;
        const int i = idx >> 4, kq = idx & 15;
        const float4 v = x4[idx];
        x_smT[kq * 4 + 0][i] = v.x;
        x_smT[kq * 4 + 1][i] = v.y;
        x_smT[kq * 4 + 2][i] = v.z;
        x_smT[kq * 4 + 3][i] = v.w;
    }
    __syncthreads();

    // ---- ybar partial: raw tile sum over 64 i ----
    {
        const int w = tid >> 6, lane = tid & 63;
        const int kk = lane >> 2, q = lane & 3;
        const int k = w * 16 + kk;
        float s = 0.f;
        #pragma unroll
        for (int m = 0; m < 4; ++m) {
            const float4 v = *(const float4*)&x_smT[k][q * 16 + m * 4];
            s += v.x + v.y + v.z + v.w;
        }
        s += __shfl_xor(s, 1, 64);
        s += __shfl_xor(s, 2, 64);
        if (q == 0) cohstore1(&ypb[t * KK + k], s);
    }
    cohfence();
    __syncthreads();
    if (tid == 0)
        role_sm = __hip_atomic_fetch_add(&cnt0[0], 1, __ATOMIC_RELAXED, __HIP_MEMORY_SCOPE_AGENT);
    __syncthreads();
    const int r0 = role_sm;

    if (r0 >= NT - NCAPS) {
        wait_ge(cnt0, NT);
        caps_tail<0>(b, r0 - (NT - NCAPS), W, ypb, wvb, out, scratch);
        cohfence();
        __syncthreads();
        if (tid == 0 &&
            __hip_atomic_fetch_add(&cnt0b[0], 1, __ATOMIC_RELAXED, __HIP_MEMORY_SCOPE_AGENT) == NCAPS - 1)
            __hip_atomic_store(&flag1[0], 1, __ATOMIC_RELAXED, __HIP_MEMORY_SCOPE_AGENT);
    }
    wait_ge(flag1, 1);

    route_pass(wvb, ypb + (size_t)t * JJ * KK, x_smT, scratch);   // pass 1

    cohfence();
    __syncthreads();
    if (tid == 0)
        role_sm = __hip_atomic_fetch_add(&cnt1[0], 1, __ATOMIC_RELAXED, __HIP_MEMORY_SCOPE_AGENT);
    __syncthreads();
    const int r1 = role_sm;

    if (r1 >= NT - NCAPS) {
        wait_ge(cnt1, NT);
        caps_tail<1>(b, r1 - (NT - NCAPS), W, ypb, wvb, out, scratch);
        cohfence();
        __syncthreads();
        if (tid == 0 &&
            __hip_atomic_fetch_add(&cnt1b[0], 1, __ATOMIC_RELAXED, __HIP_MEMORY_SCOPE_AGENT) == NCAPS - 1)
            __hip_atomic_store(&flag2[0], 1, __ATOMIC_RELAXED, __HIP_MEMORY_SCOPE_AGENT);
    }
    wait_ge(flag2, 1);

    route_pass(wvb, ypb + (size_t)t * JJ * KK, x_smT, scratch);   // pass 2

    cohfence();
    __syncthreads();
    if (tid == 0)
        role_sm = __hip_atomic_fetch_add(&cnt2[0], 1, __ATOMIC_RELAXED, __HIP_MEMORY_SCOPE_AGENT);
    __syncthreads();
    const int r2 = role_sm;

    if (r2 >= NT - NCAPS) {
        wait_ge(cnt2, NT);
        caps_tail<2>(b, r2 - (NT - NCAPS), W, ypb, wvb, out, scratch);
    }
}

// ---------------------------------------------------------------------------
// Workspace (floats): wv[65536] | ypart[2097152] | sync[7168 ints = 28KB]
// ybar partials live inside ypart[b] (dead before route1 overwrites them).
// ---------------------------------------------------------------------------
extern "C" void kernel_launch(void* const* d_in, const int* in_sizes, int n_in,
                              void* d_out, int out_size, void* d_ws, size_t ws_size,
                              hipStream_t stream) {
    (void)in_sizes; (void)n_in; (void)out_size; (void)ws_size;
    const float* x = (const float*)d_in[0];
    const float* W = (const float*)d_in[1];
    float* out = (float*)d_out;
    float* ws = (float*)d_ws;

    float* wv = ws;                         // 65536 floats
    float* ypart = ws + 65536;              // 2097152 floats
    int* sync = (int*)(ws + 65536 + 2097152);

    hipMemsetAsync(sync, 0, SYNC_INTS * sizeof(int), stream);
    fused_kernel<<<dim3(BB * NT), dim3(256), 0, stream>>>(x, W, wv, ypart, out, sync);
}

// Round 7
// 99.540 us; speedup vs baseline: 5.9775x; 1.0075x over previous
//
#include <hip/hip_runtime.h>
#include <math.h>

// RoutingCapsules — B=16, I=2048, K=64, J=64, D=32, 3 routing iters.
//   s[b,j,d]  = sum_k W[j,d,k] y[b,j,k],    y[b,j,k]  = sum_i c[b,j,i] x[b,i,k]
//   uv[b,j,i] = sum_k x[b,i,k] wv[b,j,k],   wv[b,j,k] = sum_d W[j,d,k] v[b,j,d]
// Iter-1 c uniform -> y1 = (1/64) sum_i x.  Logits linear in wv -> wv2 = wv1+dwv.
//
// R8 = R7 with the squash-reduction bug fixed: step (D)'s butterfly over lane
// bits 2..5 already counts each d exactly once per (bit0,bit1) class, so the
// "ps *= 0.25f" compensation was wrong (made ||s||^2 4x small -> absmax 5e-2).
//
// R7 design (on top of R6's uncached-dwordx4 zero-fence):
//  * caps distributed: block t owns j={2t,2t+1} -> 4x caps parallelism, no
//    idle 3/4-chip tail phase, wv[j] block-private -> lives in a REG.
//  * W held in VGPRs (4 float4/thread, loaded once).
//  * sync = per-block flag array (done[b][t] = phase, monotonic 1..5) polled
//    by one coalesced 32-lane uncached gather + __all. No atomics.

#define BB 16
#define II 2048
#define KK 64
#define JJ 64
#define DD 32
#define ITILE 64
#define NT 32              // i-tiles per b; block t of b owns j = {2t, 2t+1}

#define SCRATCH_FLOATS ((KK + JJ) * 68 + 8 * 72)   // 9280 floats = 37120 B

#define PH_YBAR   1
#define PH_CAPS0  2
#define PH_ROUTE1 3
#define PH_CAPS1  4
#define PH_ROUTE2 5

#define SYNC_INTS (BB * 64)    // 32 flags per b, padded to 64 ints (256 B)

typedef float f32x4 __attribute__((ext_vector_type(4)));

// ---- coherent (cache-bypassing) accessors, async; value valid after cohwait0 ----
__device__ __forceinline__ f32x4 cohload4a(const float* p) {
    f32x4 t;
    asm volatile("global_load_dwordx4 %0, %1, off sc0 sc1"
                 : "=&v"(t) : "v"(p) : "memory");
    return t;
}
__device__ __forceinline__ int cohload1ia(const int* p) {
    int t;
    asm volatile("global_load_dword %0, %1, off sc0 sc1"
                 : "=&v"(t) : "v"(p) : "memory");
    return t;
}
__device__ __forceinline__ void cohwait0() {
    asm volatile("s_waitcnt vmcnt(0)" ::: "memory");
    __builtin_amdgcn_sched_barrier(0);   // rule #18: pin uses after the wait
}
__device__ __forceinline__ void cohstore4(float* p, f32x4 v) {
    asm volatile("global_store_dwordx4 %0, %1, off sc0 sc1"
                 :: "v"(p), "v"(v) : "memory");
}
__device__ __forceinline__ void cohstore1(float* p, float v) {
    asm volatile("global_store_dword %0, %1, off sc0 sc1"
                 :: "v"(p), "v"(v) : "memory");
}
__device__ __forceinline__ void cohstore1i(int* p, int v) {
    asm volatile("global_store_dword %0, %1, off sc0 sc1"
                 :: "v"(p), "v"(v) : "memory");
}
__device__ __forceinline__ void cohfence() {   // drain this wave's stores
    asm volatile("s_waitcnt vmcnt(0)" ::: "memory");
}

// flag: done[b][t] = phase (single writer per slot, monotonic)
__device__ __forceinline__ void set_phase(int* slot, int phase) {
    if (threadIdx.x == 0) cohstore1i(slot, phase);
}
// wave-0: one coalesced uncached gather of all 32 flags + __all
__device__ __forceinline__ void wait_all(const int* done_b, int phase) {
    if (threadIdx.x < 64) {
        const int* p = done_b + (threadIdx.x & 31);
        for (;;) {
            int v = cohload1ia(p);
            cohwait0();
            if (__all(v >= phase)) break;
            __builtin_amdgcn_s_sleep(4);
        }
    }
    __syncthreads();
}

// ---------------------------------------------------------------------------
// caps phase: this block's 2 j. W in regs (w0..w3 = W[j0+jr, d, kq4*16..+15]).
//   MODE 0: y = (1/64)*sum_t ybarp[t][k];  wv_reg  = W^T v; store wv
//   MODE 1: y = sum_t ypart[t][j][k];      wv_reg += W^T v; store wv
//   MODE 2: y = sum_t ypart[t][j][k];      out = squash(s)
// Thread map: jr = tid>>7, rem = tid&127, d = rem>>2, kq4 = rem&3.
// ---------------------------------------------------------------------------
template <int MODE>
__device__ __forceinline__ void caps_phase(
    int b, int j0, float4 w0, float4 w1, float4 w2, float4 w3,
    const float* __restrict__ ypb, float* __restrict__ wvb,
    float* __restrict__ out, float* scratch, float& wv_reg) {
    const int tid = threadIdx.x;
    const int wave = tid >> 6, lane = tid & 63;
    const int jr = tid >> 7, rem = tid & 127;

    float* y_sm   = scratch;          // [2][64]
    float* wvp_sm = scratch + 128;    // [2][2][64]
    float* sq_sm  = scratch + 384;    // [2][2]

    // (A) y-reduce: wave w -> j-slot jw=w>>1, k-half=(w&1)*32; lanes: kq8,th
    {
        const int jw = wave >> 1;
        const int khalf = (wave & 1) * 32;
        const int kq8 = lane & 7, th = lane >> 3;
        f32x4 vb[4];
        if (MODE == 0) {
            #pragma unroll
            for (int n = 0; n < 4; ++n)
                vb[n] = cohload4a(ypb + (size_t)(th + n * 8) * KK + khalf + kq8 * 4);
        } else {
            const int jA = j0 + jw;
            #pragma unroll
            for (int n = 0; n < 4; ++n)
                vb[n] = cohload4a(ypb + ((size_t)(th + n * 8) * JJ + jA) * KK + khalf + kq8 * 4);
        }
        cohwait0();
        float a0 = vb[0][0] + vb[1][0] + vb[2][0] + vb[3][0];
        float a1 = vb[0][1] + vb[1][1] + vb[2][1] + vb[3][1];
        float a2 = vb[0][2] + vb[1][2] + vb[2][2] + vb[3][2];
        float a3 = vb[0][3] + vb[1][3] + vb[2][3] + vb[3][3];
        #pragma unroll
        for (int m = 8; m <= 32; m <<= 1) {     // reduce over th (lane bits 3..5)
            a0 += __shfl_xor(a0, m, 64);
            a1 += __shfl_xor(a1, m, 64);
            a2 += __shfl_xor(a2, m, 64);
            a3 += __shfl_xor(a3, m, 64);
        }
        if (MODE == 0) {
            a0 *= (1.f / 64.f); a1 *= (1.f / 64.f);
            a2 *= (1.f / 64.f); a3 *= (1.f / 64.f);
        }
        if (th == 0)
            *(float4*)&y_sm[jw * 64 + khalf + kq8 * 4] = make_float4(a0, a1, a2, a3);
    }
    __syncthreads();

    // (C) s[j,d] = dot(W[j,d,:], y[j,:]) — 4 threads per (j,d), 16 k each
    const int d = rem >> 2, kq4 = rem & 3;
    float sv;
    {
        const float* yb = y_sm + jr * 64 + kq4 * 16;
        const float4 y0 = *(const float4*)(yb + 0);
        const float4 y1 = *(const float4*)(yb + 4);
        const float4 y2 = *(const float4*)(yb + 8);
        const float4 y3 = *(const float4*)(yb + 12);
        sv = w0.x * y0.x + w0.y * y0.y + w0.z * y0.z + w0.w * y0.w
           + w1.x * y1.x + w1.y * y1.y + w1.z * y1.z + w1.w * y1.w
           + w2.x * y2.x + w2.y * y2.y + w2.z * y2.z + w2.w * y2.w
           + w3.x * y3.x + w3.y * y3.y + w3.z * y3.z + w3.w * y3.w;
        sv += __shfl_xor(sv, 1, 64);   // reduce kq4 (lane bits 0..1)
        sv += __shfl_xor(sv, 2, 64);
    }

    // (D) squash: butterfly over lane bits 2..5; each (bit0,bit1) class holds
    // one lane per d -> ps = sum over this wave's 16 d of s^2 (NO overcount).
    float ps = sv * sv;
    ps += __shfl_xor(ps, 4, 64);
    ps += __shfl_xor(ps, 8, 64);
    ps += __shfl_xor(ps, 16, 64);
    ps += __shfl_xor(ps, 32, 64);
    if (lane == 0) sq_sm[jr * 2 + (wave & 1)] = ps;
    __syncthreads();
    ps = sq_sm[jr * 2] + sq_sm[jr * 2 + 1];
    const float f = ps / ((1.f + ps) * (sqrtf(ps) + 1e-8f));

    if (MODE == 2) {
        if (kq4 == 0) out[((size_t)b * JJ + j0 + jr) * DD + d] = sv * f;
        return;
    }

    // (E) wv[j,k] = sum_d W[j,d,k] v[j,d]; reduce d via shfl, halves via LDS
    const float vv = sv * f;
    float c[16];
    {
        const float4 ww[4] = {w0, w1, w2, w3};
        #pragma unroll
        for (int q = 0; q < 4; ++q) {
            c[q * 4 + 0] = ww[q].x * vv;
            c[q * 4 + 1] = ww[q].y * vv;
            c[q * 4 + 2] = ww[q].z * vv;
            c[q * 4 + 3] = ww[q].w * vv;
        }
    }
    #pragma unroll
    for (int m = 4; m <= 32; m <<= 1)
        #pragma unroll
        for (int q = 0; q < 16; ++q)
            c[q] += __shfl_xor(c[q], m, 64);
    if (lane < 4) {                    // lane == kq4, d-half sum holder
        float* wp = wvp_sm + jr * 128 + (wave & 1) * 64 + lane * 16;
        #pragma unroll
        for (int q = 0; q < 16; ++q) wp[q] = c[q];
    }
    __syncthreads();
    if (rem < 64) {
        const int k = rem;
        float tot = wvp_sm[jr * 128 + k] + wvp_sm[jr * 128 + 64 + k];
        if (MODE == 1) tot += wv_reg;
        wv_reg = tot;
        cohstore1(&wvb[(size_t)(j0 + jr) * KK + k], tot);
    }
}

// ---------------------------------------------------------------------------
// route pass (unchanged, verified R2-R6): uv = x·wv^T; softmax_j; ypt = c^T x
// ---------------------------------------------------------------------------
__device__ __forceinline__ void route_pass(const float* __restrict__ wvb,
                                           float* __restrict__ ypt,
                                           float (*x_smT)[68], float* scratch) {
    const int tid = threadIdx.x;
    float (*wv_smT)[68] = (float (*)[68])scratch;
    float (*uv_smT)[68] = (float (*)[68])(scratch + KK * 68);
    float (*red)[72]    = (float (*)[72])(scratch + (KK + JJ) * 68);

    {   // stage wv (transposed) — batched async coherent 16B loads
        f32x4 vb[4];
        #pragma unroll
        for (int n = 0; n < 4; ++n)
            vb[n] = cohload4a(wvb + (size_t)(tid + n * 256) * 4);
        cohwait0();
        #pragma unroll
        for (int n = 0; n < 4; ++n) {
            const int idx = tid + n * 256;
            const int jj = idx >> 4, kq = idx & 15;
            wv_smT[kq * 4 + 0][jj] = vb[n][0];
            wv_smT[kq * 4 + 1][jj] = vb[n][1];
            wv_smT[kq * 4 + 2][jj] = vb[n][2];
            wv_smT[kq * 4 + 3][jj] = vb[n][3];
        }
    }
    __syncthreads();

    {   // uv[j][i], 4i x 4j per thread, b128 reads
        const int ib = (tid & 15) * 4, jb = (tid >> 4) * 4;
        float acc[4][4] = {};
        for (int k = 0; k < KK; ++k) {
            const float4 xv = *(const float4*)&x_smT[k][ib];
            const float4 wvv = *(const float4*)&wv_smT[k][jb];
            acc[0][0] += xv.x * wvv.x; acc[0][1] += xv.x * wvv.y;
            acc[0][2] += xv.x * wvv.z; acc[0][3] += xv.x * wvv.w;
            acc[1][0] += xv.y * wvv.x; acc[1][1] += xv.y * wvv.y;
            acc[1][2] += xv.y * wvv.z; acc[1][3] += xv.y * wvv.w;
            acc[2][0] += xv.z * wvv.x; acc[2][1] += xv.z * wvv.y;
            acc[2][2] += xv.z * wvv.z; acc[2][3] += xv.z * wvv.w;
            acc[3][0] += xv.w * wvv.x; acc[3][1] += xv.w * wvv.y;
            acc[3][2] += xv.w * wvv.z; acc[3][3] += xv.w * wvv.w;
        }
        #pragma unroll
        for (int r = 0; r < 4; ++r)
            *(float4*)&uv_smT[jb + r][ib] =
                make_float4(acc[0][r], acc[1][r], acc[2][r], acc[3][r]);
    }
    __syncthreads();

    {   // softmax over j (down columns); 16 values per wave in registers
        const int i = tid & 63;
        const int w = tid >> 6;
        const int j0 = w * 16;
        float e[16];
        float m = -1e30f;
        #pragma unroll
        for (int jj = 0; jj < 16; ++jj) {
            e[jj] = uv_smT[j0 + jj][i];
            m = fmaxf(m, e[jj]);
        }
        red[w][i] = m;
        __syncthreads();
        m = fmaxf(fmaxf(red[0][i], red[1][i]), fmaxf(red[2][i], red[3][i]));
        float s = 0.f;
        #pragma unroll
        for (int jj = 0; jj < 16; ++jj) {
            e[jj] = __expf(e[jj] - m);
            s += e[jj];
        }
        red[4 + w][i] = s;
        __syncthreads();
        const float inv = 1.f / (red[4][i] + red[5][i] + red[6][i] + red[7][i]);
        #pragma unroll
        for (int jj = 0; jj < 16; ++jj) uv_smT[j0 + jj][i] = e[jj] * inv;
    }
    __syncthreads();

    {   // ypt[j][k] = sum_i c[j][i] x[k][i], 4j x 4k per thread, b128 reads
        const int a = tid & 15;
        const int kb = (tid >> 4) * 4;
        float acc[4][4] = {};
        for (int i = 0; i < ITILE; i += 4) {
            float4 xv[4];
            #pragma unroll
            for (int c = 0; c < 4; ++c) xv[c] = *(const float4*)&x_smT[kb + c][i];
            #pragma unroll
            for (int r = 0; r < 4; ++r) {
                const float4 cv = *(const float4*)&uv_smT[a + 16 * r][i];
                #pragma unroll
                for (int c = 0; c < 4; ++c)
                    acc[r][c] += cv.x * xv[c].x + cv.y * xv[c].y +
                                 cv.z * xv[c].z + cv.w * xv[c].w;
            }
        }
        #pragma unroll
        for (int r = 0; r < 4; ++r) {
            f32x4 sv;
            sv[0] = acc[r][0]; sv[1] = acc[r][1]; sv[2] = acc[r][2]; sv[3] = acc[r][3];
            cohstore4(&ypt[(a + 16 * r) * KK + kb], sv);
        }
    }
}

// ---------------------------------------------------------------------------
__global__ __launch_bounds__(256, 2) void fused_kernel(
    const float* __restrict__ x, const float* __restrict__ W,
    float* __restrict__ wv, float* __restrict__ ypart,
    float* __restrict__ out, int* __restrict__ sync) {
    const int bid = blockIdx.x;
    const int b = bid >> 5;
    const int t = bid & 31;
    const int tid = threadIdx.x;
    const int j0 = 2 * t;

    int* done_b = sync + b * 64;            // 32 flags, 256B-padded per b
    float* wvb = wv + (size_t)b * JJ * KK;
    float* ypb = ypart + (size_t)b * NT * JJ * KK;  // ybar partials overlaid

    __shared__ alignas(16) float x_smT[KK][68];
    __shared__ alignas(16) float scratch[SCRATCH_FLOATS];

    // ---- W -> regs: thread (jr, d=rem>>2, kq4=rem&3) holds 16 k ----
    const int jr = tid >> 7, rem = tid & 127;
    const float* Wp = W + ((size_t)(j0 + jr) * DD + (rem >> 2)) * KK + (rem & 3) * 16;
    const float4 w0 = *(const float4*)(Wp + 0);
    const float4 w1 = *(const float4*)(Wp + 4);
    const float4 w2 = *(const float4*)(Wp + 8);
    const float4 w3 = *(const float4*)(Wp + 12);
    float wv_reg = 0.f;

    // ---- stage x tile (once, reused by ybar + both route passes) ----
    const float4* x4 = (const float4*)(x + ((size_t)b * II + t * ITILE) * KK);
    #pragma unroll
    for (int n = 0; n < 4; ++n) {
        const int idx = tid + n * 256;
        const int i = idx >> 4, kq = idx & 15;
        const float4 v = x4[idx];
        x_smT[kq * 4 + 0][i] = v.x;
        x_smT[kq * 4 + 1][i] = v.y;
        x_smT[kq * 4 + 2][i] = v.z;
        x_smT[kq * 4 + 3][i] = v.w;
    }
    __syncthreads();

    // ---- ybar partial: raw tile sum over 64 i ----
    {
        const int w = tid >> 6, lane = tid & 63;
        const int kk = lane >> 2, q = lane & 3;
        const int k = w * 16 + kk;
        float s = 0.f;
        #pragma unroll
        for (int m = 0; m < 4; ++m) {
            const float4 v = *(const float4*)&x_smT[k][q * 16 + m * 4];
            s += v.x + v.y + v.z + v.w;
        }
        s += __shfl_xor(s, 1, 64);
        s += __shfl_xor(s, 2, 64);
        if (q == 0) cohstore1(&ypb[t * KK + k], s);
    }
    cohfence(); __syncthreads();
    set_phase(done_b + t, PH_YBAR);
    wait_all(done_b, PH_YBAR);

    caps_phase<0>(b, j0, w0, w1, w2, w3, ypb, wvb, out, scratch, wv_reg);
    cohfence(); __syncthreads();
    set_phase(done_b + t, PH_CAPS0);
    wait_all(done_b, PH_CAPS0);

    route_pass(wvb, ypb + (size_t)t * JJ * KK, x_smT, scratch);   // pass 1
    cohfence(); __syncthreads();
    set_phase(done_b + t, PH_ROUTE1);
    wait_all(done_b, PH_ROUTE1);

    caps_phase<1>(b, j0, w0, w1, w2, w3, ypb, wvb, out, scratch, wv_reg);
    cohfence(); __syncthreads();
    set_phase(done_b + t, PH_CAPS1);
    wait_all(done_b, PH_CAPS1);

    route_pass(wvb, ypb + (size_t)t * JJ * KK, x_smT, scratch);   // pass 2
    cohfence(); __syncthreads();
    set_phase(done_b + t, PH_ROUTE2);
    wait_all(done_b, PH_ROUTE2);

    caps_phase<2>(b, j0, w0, w1, w2, w3, ypb, wvb, out, scratch, wv_reg);
}

// ---------------------------------------------------------------------------
// Workspace (floats): wv[65536] | ypart[2097152] | sync[1024 ints = 4KB]
// ybar partials live inside ypart[b] (dead before route1 overwrites them).
// ---------------------------------------------------------------------------
extern "C" void kernel_launch(void* const* d_in, const int* in_sizes, int n_in,
                              void* d_out, int out_size, void* d_ws, size_t ws_size,
                              hipStream_t stream) {
    (void)in_sizes; (void)n_in; (void)out_size; (void)ws_size;
    const float* x = (const float*)d_in[0];
    const float* W = (const float*)d_in[1];
    float* out = (float*)d_out;
    float* ws = (float*)d_ws;

    float* wv = ws;                         // 65536 floats
    float* ypart = ws + 65536;              // 2097152 floats
    int* sync = (int*)(ws + 65536 + 2097152);

    hipMemsetAsync(sync, 0, SYNC_INTS * sizeof(int), stream);
    fused_kernel<<<dim3(BB * NT), dim3(256), 0, stream>>>(x, W, wv, ypart, out, sync);
}